// Round 1
// baseline (4409.027 us; speedup 1.0000x reference)
//
#include <hip/hip_runtime.h>
#include <math.h>

#define NEG 0.2f

// ---------------------------------------------------------------------------
// K1: h1[N,64] = x[N,512] @ W1[512,64]   (f32, LDS-tiled 64 rows x 64 cols, K-chunk 32)
// ---------------------------------------------------------------------------
__global__ __launch_bounds__(256) void gemm1_k(const float* __restrict__ x,
                                               const float* __restrict__ W1,
                                               float* __restrict__ h1, int Nn)
{
    const int TK = 32;
    __shared__ float xs[TK][68];  // xs[k][row]
    __shared__ float ws[TK][68];  // ws[k][col]
    int row0 = blockIdx.x * 64;
    int t = threadIdx.x;
    int tr = t >> 4, tc = t & 15;  // 16 row-groups x 16 col-groups, 4x4 each
    float acc[4][4] = {};
    for (int kb = 0; kb < 512; kb += TK) {
        // stage x tile (transposed into xs[k][r])
#pragma unroll
        for (int i = 0; i < 2; ++i) {
            int idx = t + 256 * i;        // 0..511
            int r = idx >> 3;             // 0..63
            int k4 = idx & 7;             // float4 slot 0..7
            float4 v = make_float4(0.f, 0.f, 0.f, 0.f);
            int gr = row0 + r;
            if (gr < Nn) v = *(const float4*)(x + (size_t)gr * 512 + kb + k4 * 4);
            xs[k4 * 4 + 0][r] = v.x;
            xs[k4 * 4 + 1][r] = v.y;
            xs[k4 * 4 + 2][r] = v.z;
            xs[k4 * 4 + 3][r] = v.w;
        }
        // stage W tile
#pragma unroll
        for (int i = 0; i < 2; ++i) {
            int idx = t + 256 * i;        // 0..511
            int k = idx >> 4;             // 0..31
            int c4 = idx & 15;            // 0..15
            *(float4*)&ws[k][c4 * 4] =
                *(const float4*)(W1 + (size_t)(kb + k) * 64 + c4 * 4);
        }
        __syncthreads();
#pragma unroll
        for (int kk = 0; kk < TK; ++kk) {
            float4 a = *(const float4*)&xs[kk][tr * 4];
            float4 b = *(const float4*)&ws[kk][tc * 4];
            acc[0][0] += a.x * b.x; acc[0][1] += a.x * b.y; acc[0][2] += a.x * b.z; acc[0][3] += a.x * b.w;
            acc[1][0] += a.y * b.x; acc[1][1] += a.y * b.y; acc[1][2] += a.y * b.z; acc[1][3] += a.y * b.w;
            acc[2][0] += a.z * b.x; acc[2][1] += a.z * b.y; acc[2][2] += a.z * b.z; acc[2][3] += a.z * b.w;
            acc[3][0] += a.w * b.x; acc[3][1] += a.w * b.y; acc[3][2] += a.w * b.z; acc[3][3] += a.w * b.w;
        }
        __syncthreads();
    }
#pragma unroll
    for (int i = 0; i < 4; ++i) {
        int gr = row0 + tr * 4 + i;
        if (gr < Nn) {
            float4 v = make_float4(acc[i][0], acc[i][1], acc[i][2], acc[i][3]);
            *(float4*)(h1 + (size_t)gr * 64 + tc * 4) = v;
        }
    }
}

// ---------------------------------------------------------------------------
// K2: per-(node,head) attention dots for layer 1
// ---------------------------------------------------------------------------
__global__ void attn1_k(const float* __restrict__ h1, const float* __restrict__ asrc,
                        const float* __restrict__ adst, float* __restrict__ as1,
                        float* __restrict__ ad1, int Nn)
{
    int tid = blockIdx.x * 256 + threadIdx.x;
    if (tid >= Nn * 8) return;
    int n = tid >> 3, h = tid & 7;
    const float* hp = h1 + (size_t)n * 64 + h * 8;
    float s = 0.f, d = 0.f;
#pragma unroll
    for (int c = 0; c < 8; ++c) {
        float v = hp[c];
        s += v * asrc[h * 8 + c];
        d += v * adst[h * 8 + c];
    }
    as1[tid] = s;
    ad1[tid] = d;
}

// ---------------------------------------------------------------------------
// K3: layer-1 softmax denominators (no max-shift needed: e is O(4), softmax
// is shift-invariant and EPS=1e-16 is below f32 resolution)
// ---------------------------------------------------------------------------
__global__ void edge1_denom_k(const int* __restrict__ ei, int E, int Nn,
                              const float* __restrict__ as1,
                              const float* __restrict__ ad1,
                              float* __restrict__ denom1)
{
    int tid = blockIdx.x * 256 + threadIdx.x;
    int Ep = E + Nn;
    if (tid >= Ep * 8) return;
    int e = tid >> 3, h = tid & 7;
    int s, d;
    if (e < E) { s = ei[e]; d = ei[E + e]; } else { s = d = e - E; }
    float v = as1[s * 8 + h] + ad1[d * 8 + h];
    v = v > 0.f ? v : NEG * v;
    atomicAdd(&denom1[d * 8 + h], expf(v));
}

// ---------------------------------------------------------------------------
// K4: layer-1 alpha-weighted aggregation (8 threads/edge, one per head)
// ---------------------------------------------------------------------------
__global__ void edge1_agg_k(const int* __restrict__ ei, int E, int Nn,
                            const float* __restrict__ as1,
                            const float* __restrict__ ad1,
                            const float* __restrict__ denom1,
                            const float* __restrict__ h1,
                            float* __restrict__ out1)
{
    int tid = blockIdx.x * 256 + threadIdx.x;
    int Ep = E + Nn;
    if (tid >= Ep * 8) return;
    int e = tid >> 3, h = tid & 7;
    int s, d;
    if (e < E) { s = ei[e]; d = ei[E + e]; } else { s = d = e - E; }
    float v = as1[s * 8 + h] + ad1[d * 8 + h];
    v = v > 0.f ? v : NEG * v;
    float alpha = expf(v) / (denom1[d * 8 + h] + 1e-16f);
    const float* hp = h1 + (size_t)s * 64 + h * 8;
    float* op = out1 + (size_t)d * 64 + h * 8;
#pragma unroll
    for (int c = 0; c < 8; ++c) atomicAdd(&op[c], alpha * hp[c]);
}

// ---------------------------------------------------------------------------
// K5: fused bias + ELU + GEMM2(64x10) + layer-2 attention dots (thread/node)
// ---------------------------------------------------------------------------
__global__ void node2_k(const float* __restrict__ out1, const float* __restrict__ b1,
                        const float* __restrict__ W2, const float* __restrict__ as2w,
                        const float* __restrict__ ad2w, float* __restrict__ h2,
                        float* __restrict__ as2, float* __restrict__ ad2, int Nn)
{
    int n = blockIdx.x * 256 + threadIdx.x;
    if (n >= Nn) return;
    float g[64];
#pragma unroll
    for (int c = 0; c < 64; ++c) {
        float v = out1[(size_t)n * 64 + c] + b1[c];
        g[c] = v > 0.f ? v : expm1f(v);
    }
    float acc[10] = {};
#pragma unroll
    for (int k = 0; k < 64; ++k) {
#pragma unroll
        for (int j = 0; j < 10; ++j) acc[j] += g[k] * W2[k * 10 + j];
    }
    float s = 0.f, d = 0.f;
#pragma unroll
    for (int j = 0; j < 10; ++j) {
        h2[(size_t)n * 10 + j] = acc[j];
        s += acc[j] * as2w[j];
        d += acc[j] * ad2w[j];
    }
    as2[n] = s;
    ad2[n] = d;
}

// ---------------------------------------------------------------------------
// K6 / K7: layer-2 edge passes (1 head)
// ---------------------------------------------------------------------------
__global__ void edge2_denom_k(const int* __restrict__ ei, int E, int Nn,
                              const float* __restrict__ as2,
                              const float* __restrict__ ad2,
                              float* __restrict__ denom2)
{
    int e = blockIdx.x * 256 + threadIdx.x;
    int Ep = E + Nn;
    if (e >= Ep) return;
    int s, d;
    if (e < E) { s = ei[e]; d = ei[E + e]; } else { s = d = e - E; }
    float v = as2[s] + ad2[d];
    v = v > 0.f ? v : NEG * v;
    atomicAdd(&denom2[d], expf(v));
}

__global__ void edge2_agg_k(const int* __restrict__ ei, int E, int Nn,
                            const float* __restrict__ as2,
                            const float* __restrict__ ad2,
                            const float* __restrict__ denom2,
                            const float* __restrict__ h2,
                            float* __restrict__ out2)
{
    int e = blockIdx.x * 256 + threadIdx.x;
    int Ep = E + Nn;
    if (e >= Ep) return;
    int s, d;
    if (e < E) { s = ei[e]; d = ei[E + e]; } else { s = d = e - E; }
    float v = as2[s] + ad2[d];
    v = v > 0.f ? v : NEG * v;
    float alpha = expf(v) / (denom2[d] + 1e-16f);
#pragma unroll
    for (int j = 0; j < 10; ++j)
        atomicAdd(&out2[(size_t)d * 10 + j], alpha * h2[(size_t)s * 10 + j]);
}

// ---------------------------------------------------------------------------
// K8: in-place bias + log_softmax on d_out (thread/node)
// ---------------------------------------------------------------------------
__global__ void lsm_k(float* __restrict__ out, const float* __restrict__ b2, int Nn)
{
    int n = blockIdx.x * 256 + threadIdx.x;
    if (n >= Nn) return;
    float z[10];
    float m = -1e30f;
#pragma unroll
    for (int j = 0; j < 10; ++j) {
        z[j] = out[(size_t)n * 10 + j] + b2[j];
        m = fmaxf(m, z[j]);
    }
    float ssum = 0.f;
#pragma unroll
    for (int j = 0; j < 10; ++j) ssum += expf(z[j] - m);
    float lse = m + logf(ssum);
#pragma unroll
    for (int j = 0; j < 10; ++j) out[(size_t)n * 10 + j] = z[j] - lse;
}

// ---------------------------------------------------------------------------
extern "C" void kernel_launch(void* const* d_in, const int* in_sizes, int n_in,
                              void* d_out, int out_size, void* d_ws, size_t ws_size,
                              hipStream_t stream)
{
    const float* x     = (const float*)d_in[0];
    const float* W1    = (const float*)d_in[1];
    const float* asrc1 = (const float*)d_in[2];
    const float* adst1 = (const float*)d_in[3];
    const float* b1    = (const float*)d_in[4];
    const float* W2    = (const float*)d_in[5];
    const float* asrc2 = (const float*)d_in[6];
    const float* adst2 = (const float*)d_in[7];
    const float* b2    = (const float*)d_in[8];
    const int*   ei    = (const int*)d_in[9];
    float* out = (float*)d_out;

    int F  = in_sizes[1] / 64;       // 512
    int Nn = in_sizes[0] / F;        // 100000
    int E  = in_sizes[9] / 2;        // 1600000
    int Ep = E + Nn;

    float* f = (float*)d_ws;
    float* h1  = f;  f += (size_t)Nn * 64;
    float* as1 = f;  f += (size_t)Nn * 8;
    float* ad1 = f;  f += (size_t)Nn * 8;
    float* h2  = f;  f += (size_t)Nn * 10;
    float* as2 = f;  f += Nn;
    float* ad2 = f;  f += Nn;
    // zero-initialized accumulator region (contiguous for a single memset)
    float* denom1 = f;  f += (size_t)Nn * 8;
    float* out1   = f;  f += (size_t)Nn * 64;
    float* denom2 = f;  f += Nn;

    hipMemsetAsync(denom1, 0, (size_t)Nn * (8 + 64 + 1) * sizeof(float), stream);
    hipMemsetAsync(out, 0, (size_t)Nn * 10 * sizeof(float), stream);

    gemm1_k<<<(Nn + 63) / 64, 256, 0, stream>>>(x, W1, h1, Nn);
    attn1_k<<<(Nn * 8 + 255) / 256, 256, 0, stream>>>(h1, asrc1, adst1, as1, ad1, Nn);
    edge1_denom_k<<<(Ep * 8 + 255) / 256, 256, 0, stream>>>(ei, E, Nn, as1, ad1, denom1);
    edge1_agg_k<<<(Ep * 8 + 255) / 256, 256, 0, stream>>>(ei, E, Nn, as1, ad1, denom1, h1, out1);
    node2_k<<<(Nn + 255) / 256, 256, 0, stream>>>(out1, b1, W2, asrc2, adst2, h2, as2, ad2, Nn);
    edge2_denom_k<<<(Ep + 255) / 256, 256, 0, stream>>>(ei, E, Nn, as2, ad2, denom2);
    edge2_agg_k<<<(Ep + 255) / 256, 256, 0, stream>>>(ei, E, Nn, as2, ad2, denom2, h2, out);
    lsm_k<<<(Nn + 255) / 256, 256, 0, stream>>>(out, b2, Nn);
}

// Round 2
// 804.642 us; speedup vs baseline: 5.4795x; 5.4795x over previous
//
#include <hip/hip_runtime.h>
#include <math.h>

#define NEG 0.2f

// ---------------------------------------------------------------------------
// K1: h1[N,64] = x[N,512] @ W1[512,64]   (f32, LDS-tiled 64 rows x 64 cols)
// ---------------------------------------------------------------------------
__global__ __launch_bounds__(256) void gemm1_k(const float* __restrict__ x,
                                               const float* __restrict__ W1,
                                               float* __restrict__ h1, int Nn)
{
    const int TK = 32;
    __shared__ float xs[TK][68];
    __shared__ float ws[TK][68];
    int row0 = blockIdx.x * 64;
    int t = threadIdx.x;
    int tr = t >> 4, tc = t & 15;
    float acc[4][4] = {};
    for (int kb = 0; kb < 512; kb += TK) {
#pragma unroll
        for (int i = 0; i < 2; ++i) {
            int idx = t + 256 * i;
            int r = idx >> 3;
            int k4 = idx & 7;
            float4 v = make_float4(0.f, 0.f, 0.f, 0.f);
            int gr = row0 + r;
            if (gr < Nn) v = *(const float4*)(x + (size_t)gr * 512 + kb + k4 * 4);
            xs[k4 * 4 + 0][r] = v.x;
            xs[k4 * 4 + 1][r] = v.y;
            xs[k4 * 4 + 2][r] = v.z;
            xs[k4 * 4 + 3][r] = v.w;
        }
#pragma unroll
        for (int i = 0; i < 2; ++i) {
            int idx = t + 256 * i;
            int k = idx >> 4;
            int c4 = idx & 15;
            *(float4*)&ws[k][c4 * 4] =
                *(const float4*)(W1 + (size_t)(kb + k) * 64 + c4 * 4);
        }
        __syncthreads();
#pragma unroll
        for (int kk = 0; kk < TK; ++kk) {
            float4 a = *(const float4*)&xs[kk][tr * 4];
            float4 b = *(const float4*)&ws[kk][tc * 4];
            acc[0][0] += a.x * b.x; acc[0][1] += a.x * b.y; acc[0][2] += a.x * b.z; acc[0][3] += a.x * b.w;
            acc[1][0] += a.y * b.x; acc[1][1] += a.y * b.y; acc[1][2] += a.y * b.z; acc[1][3] += a.y * b.w;
            acc[2][0] += a.z * b.x; acc[2][1] += a.z * b.y; acc[2][2] += a.z * b.z; acc[2][3] += a.z * b.w;
            acc[3][0] += a.w * b.x; acc[3][1] += a.w * b.y; acc[3][2] += a.w * b.z; acc[3][3] += a.w * b.w;
        }
        __syncthreads();
    }
#pragma unroll
    for (int i = 0; i < 4; ++i) {
        int gr = row0 + tr * 4 + i;
        if (gr < Nn) {
            float4 v = make_float4(acc[i][0], acc[i][1], acc[i][2], acc[i][3]);
            *(float4*)(h1 + (size_t)gr * 64 + tc * 4) = v;
        }
    }
}

// ---------------------------------------------------------------------------
// K2: per-(node,head) attention dots for layer 1
// ---------------------------------------------------------------------------
__global__ void attn1_k(const float* __restrict__ h1, const float* __restrict__ asrc,
                        const float* __restrict__ adst, float* __restrict__ as1,
                        float* __restrict__ ad1, int Nn)
{
    int tid = blockIdx.x * 256 + threadIdx.x;
    if (tid >= Nn * 8) return;
    int n = tid >> 3, h = tid & 7;
    const float* hp = h1 + (size_t)n * 64 + h * 8;
    float s = 0.f, d = 0.f;
#pragma unroll
    for (int c = 0; c < 8; ++c) {
        float v = hp[c];
        s += v * asrc[h * 8 + c];
        d += v * adst[h * 8 + c];
    }
    as1[tid] = s;
    ad1[tid] = d;
}

// ---------------------------------------------------------------------------
// CSR build: histogram -> 3-kernel exclusive scan -> scatter (by dst)
// ---------------------------------------------------------------------------
__global__ void hist_k(const int* __restrict__ ei, int E, int Nn, int* __restrict__ deg)
{
    int e = blockIdx.x * 256 + threadIdx.x;
    int Ep = E + Nn;
    if (e >= Ep) return;
    int d = (e < E) ? ei[E + e] : e - E;
    atomicAdd(&deg[d], 1);
}

// block = 256 threads, 1024 elements/block
__global__ void scan_a_k(const int* __restrict__ deg, int Nn, int* __restrict__ bsum)
{
    __shared__ int tmp[256];
    int t = threadIdx.x;
    int base = blockIdx.x * 1024 + t * 4;
    int s = 0;
#pragma unroll
    for (int j = 0; j < 4; ++j) { int i = base + j; if (i < Nn) s += deg[i]; }
    tmp[t] = s;
    __syncthreads();
    for (int off = 1; off < 256; off <<= 1) {
        int a = (t >= off) ? tmp[t - off] : 0;
        __syncthreads();
        tmp[t] += a;
        __syncthreads();
    }
    if (t == 255) bsum[blockIdx.x] = tmp[255];
}

// single block; nb <= 256
__global__ void scan_b_k(int* __restrict__ bsum, int nb)
{
    __shared__ int tmp[256];
    int t = threadIdx.x;
    int v = (t < nb) ? bsum[t] : 0;
    tmp[t] = v;
    __syncthreads();
    for (int off = 1; off < 256; off <<= 1) {
        int a = (t >= off) ? tmp[t - off] : 0;
        __syncthreads();
        tmp[t] += a;
        __syncthreads();
    }
    if (t < nb) bsum[t] = tmp[t] - v;  // exclusive
}

__global__ void scan_c_k(const int* __restrict__ deg, int Nn, const int* __restrict__ boff,
                         int* __restrict__ rowptr, int* __restrict__ cursor)
{
    __shared__ int tmp[256];
    int t = threadIdx.x;
    int base = blockIdx.x * 1024 + t * 4;
    int v[4];
    int s = 0;
#pragma unroll
    for (int j = 0; j < 4; ++j) {
        int i = base + j;
        v[j] = (i < Nn) ? deg[i] : 0;
        s += v[j];
    }
    tmp[t] = s;
    __syncthreads();
    for (int off = 1; off < 256; off <<= 1) {
        int a = (t >= off) ? tmp[t - off] : 0;
        __syncthreads();
        tmp[t] += a;
        __syncthreads();
    }
    int excl = boff[blockIdx.x] + tmp[t] - s;
#pragma unroll
    for (int j = 0; j < 4; ++j) {
        int i = base + j;
        if (i < Nn) { rowptr[i] = excl; cursor[i] = excl; excl += v[j]; }
    }
}

__global__ void scat_k(const int* __restrict__ ei, int E, int Nn,
                       int* __restrict__ cursor, int* __restrict__ csr)
{
    int e = blockIdx.x * 256 + threadIdx.x;
    int Ep = E + Nn;
    if (e >= Ep) return;
    int s, d;
    if (e < E) { s = ei[e]; d = ei[E + e]; } else { s = d = e - E; }
    int idx = atomicAdd(&cursor[d], 1);
    csr[idx] = s;
}

// ---------------------------------------------------------------------------
// Layer-1 fused softmax+aggregate: one wave per dst node, lane = head*8+chan.
// p replicated across the 8 chan-lanes of a head -> denominator needs no
// cross-lane reduction. Single pass (softmax shift-invariant, e is O(1)).
// ---------------------------------------------------------------------------
__global__ __launch_bounds__(256) void agg1_k(const int* __restrict__ csr,
                                              const int* __restrict__ rowptr,
                                              const int* __restrict__ deg,
                                              const float* __restrict__ as1,
                                              const float* __restrict__ ad1,
                                              const float* __restrict__ h1,
                                              float* __restrict__ out1, int Nn)
{
    int wid = (blockIdx.x * 256 + threadIdx.x) >> 6;
    if (wid >= Nn) return;
    int lane = threadIdx.x & 63;
    int h = lane >> 3;
    float adv = ad1[wid * 8 + h];
    int start = rowptr[wid];
    int len = deg[wid];
    float accp = 0.f, accv = 0.f;
    for (int i = 0; i < len; ++i) {
        int s = csr[start + i];
        float e = as1[s * 8 + h] + adv;
        e = e > 0.f ? e : NEG * e;
        float p = __expf(e);
        accp += p;
        accv += p * h1[(size_t)s * 64 + lane];
    }
    out1[(size_t)wid * 64 + lane] = accv / (accp + 1e-16f);
}

// ---------------------------------------------------------------------------
// K5: fused bias + ELU + GEMM2(64x10) + layer-2 attention dots (thread/node)
// ---------------------------------------------------------------------------
__global__ void node2_k(const float* __restrict__ out1, const float* __restrict__ b1,
                        const float* __restrict__ W2, const float* __restrict__ as2w,
                        const float* __restrict__ ad2w, float* __restrict__ h2,
                        float* __restrict__ as2, float* __restrict__ ad2, int Nn)
{
    int n = blockIdx.x * 256 + threadIdx.x;
    if (n >= Nn) return;
    float g[64];
#pragma unroll
    for (int c = 0; c < 64; ++c) {
        float v = out1[(size_t)n * 64 + c] + b1[c];
        g[c] = v > 0.f ? v : expm1f(v);
    }
    float acc[10] = {};
#pragma unroll
    for (int k = 0; k < 64; ++k) {
#pragma unroll
        for (int j = 0; j < 10; ++j) acc[j] += g[k] * W2[k * 10 + j];
    }
    float s = 0.f, d = 0.f;
#pragma unroll
    for (int j = 0; j < 10; ++j) {
        h2[(size_t)n * 10 + j] = acc[j];
        s += acc[j] * as2w[j];
        d += acc[j] * ad2w[j];
    }
    as2[n] = s;
    ad2[n] = d;
}

// ---------------------------------------------------------------------------
// Layer-2 fused softmax+aggregate: 16 threads per dst (lanes 0..9 = channels)
// ---------------------------------------------------------------------------
__global__ __launch_bounds__(256) void agg2_k(const int* __restrict__ csr,
                                              const int* __restrict__ rowptr,
                                              const int* __restrict__ deg,
                                              const float* __restrict__ as2,
                                              const float* __restrict__ ad2,
                                              const float* __restrict__ h2,
                                              float* __restrict__ out, int Nn)
{
    int g = (blockIdx.x * 256 + threadIdx.x) >> 4;
    if (g >= Nn) return;
    int c = threadIdx.x & 15;
    float adv = ad2[g];
    int start = rowptr[g];
    int len = deg[g];
    float accp = 0.f, accv = 0.f;
    for (int i = 0; i < len; ++i) {
        int s = csr[start + i];
        float e = as2[s] + adv;
        e = e > 0.f ? e : NEG * e;
        float p = __expf(e);
        accp += p;
        if (c < 10) accv += p * h2[(size_t)s * 10 + c];
    }
    if (c < 10) out[(size_t)g * 10 + c] = accv / (accp + 1e-16f);
}

// ---------------------------------------------------------------------------
// K8: in-place bias + log_softmax on d_out (thread/node)
// ---------------------------------------------------------------------------
__global__ void lsm_k(float* __restrict__ out, const float* __restrict__ b2, int Nn)
{
    int n = blockIdx.x * 256 + threadIdx.x;
    if (n >= Nn) return;
    float z[10];
    float m = -1e30f;
#pragma unroll
    for (int j = 0; j < 10; ++j) {
        z[j] = out[(size_t)n * 10 + j] + b2[j];
        m = fmaxf(m, z[j]);
    }
    float ssum = 0.f;
#pragma unroll
    for (int j = 0; j < 10; ++j) ssum += expf(z[j] - m);
    float lse = m + logf(ssum);
#pragma unroll
    for (int j = 0; j < 10; ++j) out[(size_t)n * 10 + j] = z[j] - lse;
}

// ---------------------------------------------------------------------------
extern "C" void kernel_launch(void* const* d_in, const int* in_sizes, int n_in,
                              void* d_out, int out_size, void* d_ws, size_t ws_size,
                              hipStream_t stream)
{
    const float* x     = (const float*)d_in[0];
    const float* W1    = (const float*)d_in[1];
    const float* asrc1 = (const float*)d_in[2];
    const float* adst1 = (const float*)d_in[3];
    const float* b1    = (const float*)d_in[4];
    const float* W2    = (const float*)d_in[5];
    const float* asrc2 = (const float*)d_in[6];
    const float* adst2 = (const float*)d_in[7];
    const float* b2    = (const float*)d_in[8];
    const int*   ei    = (const int*)d_in[9];
    float* out = (float*)d_out;

    int F  = in_sizes[1] / 64;       // 512
    int Nn = in_sizes[0] / F;        // 100000
    int E  = in_sizes[9] / 2;        // 1600000
    int Ep = E + Nn;
    int nb = (Nn + 1023) / 1024;     // scan blocks (98 <= 256)

    float* f = (float*)d_ws;
    float* h1   = f;  f += (size_t)Nn * 64;
    float* as1  = f;  f += (size_t)Nn * 8;
    float* ad1  = f;  f += (size_t)Nn * 8;
    float* h2   = f;  f += (size_t)Nn * 10;
    float* as2  = f;  f += Nn;
    float* ad2  = f;  f += Nn;
    float* out1 = f;  f += (size_t)Nn * 64;
    int* ip = (int*)f;
    int* deg    = ip;  ip += Nn;
    int* rowptr = ip;  ip += Nn;
    int* cursor = ip;  ip += Nn;
    int* bsum   = ip;  ip += 256;
    int* csr    = ip;  ip += Ep;

    // CSR build (shared by both layers)
    hipMemsetAsync(deg, 0, (size_t)Nn * sizeof(int), stream);
    hist_k<<<(Ep + 255) / 256, 256, 0, stream>>>(ei, E, Nn, deg);
    scan_a_k<<<nb, 256, 0, stream>>>(deg, Nn, bsum);
    scan_b_k<<<1, 256, 0, stream>>>(bsum, nb);
    scan_c_k<<<nb, 256, 0, stream>>>(deg, Nn, bsum, rowptr, cursor);
    scat_k<<<(Ep + 255) / 256, 256, 0, stream>>>(ei, E, Nn, cursor, csr);

    // Layer 1
    gemm1_k<<<(Nn + 63) / 64, 256, 0, stream>>>(x, W1, h1, Nn);
    attn1_k<<<(Nn * 8 + 255) / 256, 256, 0, stream>>>(h1, asrc1, adst1, as1, ad1, Nn);
    agg1_k<<<(Nn * 64 + 255) / 256, 256, 0, stream>>>(csr, rowptr, deg, as1, ad1, h1, out1, Nn);

    // Layer 2
    node2_k<<<(Nn + 255) / 256, 256, 0, stream>>>(out1, b1, W2, asrc2, adst2, h2, as2, ad2, Nn);
    agg2_k<<<(Nn * 16 + 255) / 256, 256, 0, stream>>>(csr, rowptr, deg, as2, ad2, h2, out, Nn);
    lsm_k<<<(Nn + 255) / 256, 256, 0, stream>>>(out, b2, Nn);
}

// Round 3
// 685.080 us; speedup vs baseline: 6.4358x; 1.1745x over previous
//
#include <hip/hip_runtime.h>
#include <math.h>

#define NEG 0.2f

// ---------------------------------------------------------------------------
// K1: h1[N,64] = x[N,512] @ W1[512,64]   (f32, LDS-tiled 64 rows x 64 cols)
// ---------------------------------------------------------------------------
__global__ __launch_bounds__(256) void gemm1_k(const float* __restrict__ x,
                                               const float* __restrict__ W1,
                                               float* __restrict__ h1, int Nn)
{
    const int TK = 32;
    __shared__ float xs[TK][68];
    __shared__ float ws[TK][68];
    int row0 = blockIdx.x * 64;
    int t = threadIdx.x;
    int tr = t >> 4, tc = t & 15;
    float acc[4][4] = {};
    for (int kb = 0; kb < 512; kb += TK) {
#pragma unroll
        for (int i = 0; i < 2; ++i) {
            int idx = t + 256 * i;
            int r = idx >> 3;
            int k4 = idx & 7;
            float4 v = make_float4(0.f, 0.f, 0.f, 0.f);
            int gr = row0 + r;
            if (gr < Nn) v = *(const float4*)(x + (size_t)gr * 512 + kb + k4 * 4);
            xs[k4 * 4 + 0][r] = v.x;
            xs[k4 * 4 + 1][r] = v.y;
            xs[k4 * 4 + 2][r] = v.z;
            xs[k4 * 4 + 3][r] = v.w;
        }
#pragma unroll
        for (int i = 0; i < 2; ++i) {
            int idx = t + 256 * i;
            int k = idx >> 4;
            int c4 = idx & 15;
            *(float4*)&ws[k][c4 * 4] =
                *(const float4*)(W1 + (size_t)(kb + k) * 64 + c4 * 4);
        }
        __syncthreads();
#pragma unroll
        for (int kk = 0; kk < TK; ++kk) {
            float4 a = *(const float4*)&xs[kk][tr * 4];
            float4 b = *(const float4*)&ws[kk][tc * 4];
            acc[0][0] += a.x * b.x; acc[0][1] += a.x * b.y; acc[0][2] += a.x * b.z; acc[0][3] += a.x * b.w;
            acc[1][0] += a.y * b.x; acc[1][1] += a.y * b.y; acc[1][2] += a.y * b.z; acc[1][3] += a.y * b.w;
            acc[2][0] += a.z * b.x; acc[2][1] += a.z * b.y; acc[2][2] += a.z * b.z; acc[2][3] += a.z * b.w;
            acc[3][0] += a.w * b.x; acc[3][1] += a.w * b.y; acc[3][2] += a.w * b.z; acc[3][3] += a.w * b.w;
        }
        __syncthreads();
    }
#pragma unroll
    for (int i = 0; i < 4; ++i) {
        int gr = row0 + tr * 4 + i;
        if (gr < Nn) {
            float4 v = make_float4(acc[i][0], acc[i][1], acc[i][2], acc[i][3]);
            *(float4*)(h1 + (size_t)gr * 64 + tc * 4) = v;
        }
    }
}

// ---------------------------------------------------------------------------
// K2: per-(node,head) attention dots for layer 1
// ---------------------------------------------------------------------------
__global__ void attn1_k(const float* __restrict__ h1, const float* __restrict__ asrc,
                        const float* __restrict__ adst, float* __restrict__ as1,
                        float* __restrict__ ad1, int Nn)
{
    int tid = blockIdx.x * 256 + threadIdx.x;
    if (tid >= Nn * 8) return;
    int n = tid >> 3, h = tid & 7;
    const float* hp = h1 + (size_t)n * 64 + h * 8;
    float s = 0.f, d = 0.f;
#pragma unroll
    for (int c = 0; c < 8; ++c) {
        float v = hp[c];
        s += v * asrc[h * 8 + c];
        d += v * adst[h * 8 + c];
    }
    as1[tid] = s;
    ad1[tid] = d;
}

// ---------------------------------------------------------------------------
// CSR build: histogram -> 3-kernel exclusive scan -> scatter (by dst)
// ---------------------------------------------------------------------------
__global__ void hist_k(const int* __restrict__ ei, int E, int Nn, int* __restrict__ deg)
{
    int e = blockIdx.x * 256 + threadIdx.x;
    int Ep = E + Nn;
    if (e >= Ep) return;
    int d = (e < E) ? ei[E + e] : e - E;
    atomicAdd(&deg[d], 1);
}

__global__ void scan_a_k(const int* __restrict__ deg, int Nn, int* __restrict__ bsum)
{
    __shared__ int tmp[256];
    int t = threadIdx.x;
    int base = blockIdx.x * 1024 + t * 4;
    int s = 0;
#pragma unroll
    for (int j = 0; j < 4; ++j) { int i = base + j; if (i < Nn) s += deg[i]; }
    tmp[t] = s;
    __syncthreads();
    for (int off = 1; off < 256; off <<= 1) {
        int a = (t >= off) ? tmp[t - off] : 0;
        __syncthreads();
        tmp[t] += a;
        __syncthreads();
    }
    if (t == 255) bsum[blockIdx.x] = tmp[255];
}

__global__ void scan_b_k(int* __restrict__ bsum, int nb)
{
    __shared__ int tmp[256];
    int t = threadIdx.x;
    int v = (t < nb) ? bsum[t] : 0;
    tmp[t] = v;
    __syncthreads();
    for (int off = 1; off < 256; off <<= 1) {
        int a = (t >= off) ? tmp[t - off] : 0;
        __syncthreads();
        tmp[t] += a;
        __syncthreads();
    }
    if (t < nb) bsum[t] = tmp[t] - v;  // exclusive
}

__global__ void scan_c_k(const int* __restrict__ deg, int Nn, const int* __restrict__ boff,
                         int* __restrict__ rowptr, int* __restrict__ cursor)
{
    __shared__ int tmp[256];
    int t = threadIdx.x;
    int base = blockIdx.x * 1024 + t * 4;
    int v[4];
    int s = 0;
#pragma unroll
    for (int j = 0; j < 4; ++j) {
        int i = base + j;
        v[j] = (i < Nn) ? deg[i] : 0;
        s += v[j];
    }
    tmp[t] = s;
    __syncthreads();
    for (int off = 1; off < 256; off <<= 1) {
        int a = (t >= off) ? tmp[t - off] : 0;
        __syncthreads();
        tmp[t] += a;
        __syncthreads();
    }
    int excl = boff[blockIdx.x] + tmp[t] - s;
#pragma unroll
    for (int j = 0; j < 4; ++j) {
        int i = base + j;
        if (i < Nn) { rowptr[i] = excl; cursor[i] = excl; excl += v[j]; }
    }
}

__global__ void scat_k(const int* __restrict__ ei, int E, int Nn,
                       int* __restrict__ cursor, int* __restrict__ csr)
{
    int e = blockIdx.x * 256 + threadIdx.x;
    int Ep = E + Nn;
    if (e >= Ep) return;
    int s, d;
    if (e < E) { s = ei[e]; d = ei[E + e]; } else { s = d = e - E; }
    int idx = atomicAdd(&cursor[d], 1);
    csr[idx] = s;
}

// ---------------------------------------------------------------------------
// Layer-1 fused softmax+aggregate: one wave per dst node.
// lane = sub*16 + c4: sub in 0..3 = edge slot (4 edges concurrently),
// c4 = float4 chunk of the 64-channel row. Manual unroll x2 -> 8 edge
// gathers in flight per wave. Epilogue: shfl_xor(16/32) reduce over sub.
// ---------------------------------------------------------------------------
__global__ __launch_bounds__(256) void agg1_k(const int* __restrict__ csr,
                                              const int* __restrict__ rowptr,
                                              const int* __restrict__ deg,
                                              const float* __restrict__ as1,
                                              const float* __restrict__ ad1,
                                              const float* __restrict__ h1,
                                              float* __restrict__ out1, int Nn)
{
    int wid = (blockIdx.x * 256 + threadIdx.x) >> 6;
    if (wid >= Nn) return;
    int lane = threadIdx.x & 63;
    int sub = lane >> 4;
    int c4 = lane & 15;          // channels 4*c4 .. 4*c4+3
    int h = c4 >> 1;             // head = (4*c4)/8
    float adv = ad1[wid * 8 + h];
    int start = rowptr[wid];
    int len = deg[wid];
    float accp = 0.f;
    float4 accv = make_float4(0.f, 0.f, 0.f, 0.f);
    int i = sub;
    for (; i + 4 < len; i += 8) {
        int s0 = csr[start + i];
        int s1 = csr[start + i + 4];
        float e0 = as1[s0 * 8 + h] + adv;
        float e1 = as1[s1 * 8 + h] + adv;
        float4 hv0 = *(const float4*)(h1 + (size_t)s0 * 64 + c4 * 4);
        float4 hv1 = *(const float4*)(h1 + (size_t)s1 * 64 + c4 * 4);
        e0 = e0 > 0.f ? e0 : NEG * e0;
        e1 = e1 > 0.f ? e1 : NEG * e1;
        float p0 = __expf(e0);
        float p1 = __expf(e1);
        accp += p0 + p1;
        accv.x += p0 * hv0.x + p1 * hv1.x;
        accv.y += p0 * hv0.y + p1 * hv1.y;
        accv.z += p0 * hv0.z + p1 * hv1.z;
        accv.w += p0 * hv0.w + p1 * hv1.w;
    }
    if (i < len) {
        int s0 = csr[start + i];
        float e0 = as1[s0 * 8 + h] + adv;
        float4 hv0 = *(const float4*)(h1 + (size_t)s0 * 64 + c4 * 4);
        e0 = e0 > 0.f ? e0 : NEG * e0;
        float p0 = __expf(e0);
        accp += p0;
        accv.x += p0 * hv0.x;
        accv.y += p0 * hv0.y;
        accv.z += p0 * hv0.z;
        accv.w += p0 * hv0.w;
    }
    // reduce over the 4 sub groups (lane bits 4,5)
    accp   += __shfl_xor(accp, 16);
    accv.x += __shfl_xor(accv.x, 16);
    accv.y += __shfl_xor(accv.y, 16);
    accv.z += __shfl_xor(accv.z, 16);
    accv.w += __shfl_xor(accv.w, 16);
    accp   += __shfl_xor(accp, 32);
    accv.x += __shfl_xor(accv.x, 32);
    accv.y += __shfl_xor(accv.y, 32);
    accv.z += __shfl_xor(accv.z, 32);
    accv.w += __shfl_xor(accv.w, 32);
    if (sub == 0) {
        float inv = 1.f / (accp + 1e-16f);
        float4 o = make_float4(accv.x * inv, accv.y * inv, accv.z * inv, accv.w * inv);
        *(float4*)(out1 + (size_t)wid * 64 + c4 * 4) = o;
    }
}

// ---------------------------------------------------------------------------
// K5: fused bias + ELU + GEMM2(64x10) + layer-2 attention dots (thread/node)
// ---------------------------------------------------------------------------
__global__ void node2_k(const float* __restrict__ out1, const float* __restrict__ b1,
                        const float* __restrict__ W2, const float* __restrict__ as2w,
                        const float* __restrict__ ad2w, float* __restrict__ h2,
                        float* __restrict__ as2, float* __restrict__ ad2, int Nn)
{
    int n = blockIdx.x * 256 + threadIdx.x;
    if (n >= Nn) return;
    float g[64];
#pragma unroll
    for (int c = 0; c < 16; ++c) {
        float4 v = *(const float4*)(out1 + (size_t)n * 64 + c * 4);
        float4 b = *(const float4*)(b1 + c * 4);
        float t0 = v.x + b.x, t1 = v.y + b.y, t2 = v.z + b.z, t3 = v.w + b.w;
        g[c * 4 + 0] = t0 > 0.f ? t0 : expm1f(t0);
        g[c * 4 + 1] = t1 > 0.f ? t1 : expm1f(t1);
        g[c * 4 + 2] = t2 > 0.f ? t2 : expm1f(t2);
        g[c * 4 + 3] = t3 > 0.f ? t3 : expm1f(t3);
    }
    float acc[10] = {};
#pragma unroll
    for (int k = 0; k < 64; ++k) {
#pragma unroll
        for (int j = 0; j < 10; ++j) acc[j] += g[k] * W2[k * 10 + j];
    }
    float s = 0.f, d = 0.f;
#pragma unroll
    for (int j = 0; j < 10; ++j) {
        h2[(size_t)n * 10 + j] = acc[j];
        s += acc[j] * as2w[j];
        d += acc[j] * ad2w[j];
    }
    as2[n] = s;
    ad2[n] = d;
}

// ---------------------------------------------------------------------------
// Layer-2 fused softmax+aggregate: one wave per dst, lane = sub*16 + c,
// sub in 0..3 edge slots, c = channel (0..9 live). Unroll x2 -> 8 in flight.
// ---------------------------------------------------------------------------
__global__ __launch_bounds__(256) void agg2_k(const int* __restrict__ csr,
                                              const int* __restrict__ rowptr,
                                              const int* __restrict__ deg,
                                              const float* __restrict__ as2,
                                              const float* __restrict__ ad2,
                                              const float* __restrict__ h2,
                                              float* __restrict__ out, int Nn)
{
    int wid = (blockIdx.x * 256 + threadIdx.x) >> 6;
    if (wid >= Nn) return;
    int lane = threadIdx.x & 63;
    int sub = lane >> 4;
    int c = lane & 15;
    float adv = ad2[wid];
    int start = rowptr[wid];
    int len = deg[wid];
    float accp = 0.f, accv = 0.f;
    int i = sub;
    for (; i + 4 < len; i += 8) {
        int s0 = csr[start + i];
        int s1 = csr[start + i + 4];
        float e0 = as2[s0] + adv;
        float e1 = as2[s1] + adv;
        float v0 = (c < 10) ? h2[(size_t)s0 * 10 + c] : 0.f;
        float v1 = (c < 10) ? h2[(size_t)s1 * 10 + c] : 0.f;
        e0 = e0 > 0.f ? e0 : NEG * e0;
        e1 = e1 > 0.f ? e1 : NEG * e1;
        float p0 = __expf(e0);
        float p1 = __expf(e1);
        accp += p0 + p1;
        accv += p0 * v0 + p1 * v1;
    }
    if (i < len) {
        int s0 = csr[start + i];
        float e0 = as2[s0] + adv;
        float v0 = (c < 10) ? h2[(size_t)s0 * 10 + c] : 0.f;
        e0 = e0 > 0.f ? e0 : NEG * e0;
        float p0 = __expf(e0);
        accp += p0;
        accv += p0 * v0;
    }
    accp += __shfl_xor(accp, 16);
    accv += __shfl_xor(accv, 16);
    accp += __shfl_xor(accp, 32);
    accv += __shfl_xor(accv, 32);
    if (sub == 0 && c < 10)
        out[(size_t)wid * 10 + c] = accv / (accp + 1e-16f);
}

// ---------------------------------------------------------------------------
// K8: in-place bias + log_softmax on d_out (thread/node)
// ---------------------------------------------------------------------------
__global__ void lsm_k(float* __restrict__ out, const float* __restrict__ b2, int Nn)
{
    int n = blockIdx.x * 256 + threadIdx.x;
    if (n >= Nn) return;
    float z[10];
    float m = -1e30f;
#pragma unroll
    for (int j = 0; j < 10; ++j) {
        z[j] = out[(size_t)n * 10 + j] + b2[j];
        m = fmaxf(m, z[j]);
    }
    float ssum = 0.f;
#pragma unroll
    for (int j = 0; j < 10; ++j) ssum += expf(z[j] - m);
    float lse = m + logf(ssum);
#pragma unroll
    for (int j = 0; j < 10; ++j) out[(size_t)n * 10 + j] = z[j] - lse;
}

// ---------------------------------------------------------------------------
extern "C" void kernel_launch(void* const* d_in, const int* in_sizes, int n_in,
                              void* d_out, int out_size, void* d_ws, size_t ws_size,
                              hipStream_t stream)
{
    const float* x     = (const float*)d_in[0];
    const float* W1    = (const float*)d_in[1];
    const float* asrc1 = (const float*)d_in[2];
    const float* adst1 = (const float*)d_in[3];
    const float* b1    = (const float*)d_in[4];
    const float* W2    = (const float*)d_in[5];
    const float* asrc2 = (const float*)d_in[6];
    const float* adst2 = (const float*)d_in[7];
    const float* b2    = (const float*)d_in[8];
    const int*   ei    = (const int*)d_in[9];
    float* out = (float*)d_out;

    int F  = in_sizes[1] / 64;       // 512
    int Nn = in_sizes[0] / F;        // 100000
    int E  = in_sizes[9] / 2;        // 1600000
    int Ep = E + Nn;
    int nb = (Nn + 1023) / 1024;

    float* f = (float*)d_ws;
    float* h1   = f;  f += (size_t)Nn * 64;
    float* as1  = f;  f += (size_t)Nn * 8;
    float* ad1  = f;  f += (size_t)Nn * 8;
    float* h2   = f;  f += (size_t)Nn * 10;
    float* as2  = f;  f += Nn;
    float* ad2  = f;  f += Nn;
    float* out1 = f;  f += (size_t)Nn * 64;
    int* ip = (int*)f;
    int* deg    = ip;  ip += Nn;
    int* rowptr = ip;  ip += Nn;
    int* cursor = ip;  ip += Nn;
    int* bsum   = ip;  ip += 256;
    int* csr    = ip;  ip += Ep;

    // CSR build (shared by both layers)
    hipMemsetAsync(deg, 0, (size_t)Nn * sizeof(int), stream);
    hist_k<<<(Ep + 255) / 256, 256, 0, stream>>>(ei, E, Nn, deg);
    scan_a_k<<<nb, 256, 0, stream>>>(deg, Nn, bsum);
    scan_b_k<<<1, 256, 0, stream>>>(bsum, nb);
    scan_c_k<<<nb, 256, 0, stream>>>(deg, Nn, bsum, rowptr, cursor);
    scat_k<<<(Ep + 255) / 256, 256, 0, stream>>>(ei, E, Nn, cursor, csr);

    // Layer 1
    gemm1_k<<<(Nn + 63) / 64, 256, 0, stream>>>(x, W1, h1, Nn);
    attn1_k<<<(Nn * 8 + 255) / 256, 256, 0, stream>>>(h1, asrc1, adst1, as1, ad1, Nn);
    agg1_k<<<(Nn * 64 + 255) / 256, 256, 0, stream>>>(csr, rowptr, deg, as1, ad1, h1, out1, Nn);

    // Layer 2
    node2_k<<<(Nn + 255) / 256, 256, 0, stream>>>(out1, b1, W2, asrc2, adst2, h2, as2, ad2, Nn);
    agg2_k<<<(Nn * 64 + 255) / 256, 256, 0, stream>>>(csr, rowptr, deg, as2, ad2, h2, out, Nn);
    lsm_k<<<(Nn + 255) / 256, 256, 0, stream>>>(out, b2, Nn);
}

// Round 4
// 602.388 us; speedup vs baseline: 7.3193x; 1.1373x over previous
//
#include <hip/hip_runtime.h>
#include <math.h>

#define NEG 0.2f

// ---------------------------------------------------------------------------
// K1: h1[N,64] = x[N,512] @ W1[512,64]   (f32, LDS-tiled 64 rows x 64 cols)
// ---------------------------------------------------------------------------
__global__ __launch_bounds__(256) void gemm1_k(const float* __restrict__ x,
                                               const float* __restrict__ W1,
                                               float* __restrict__ h1, int Nn)
{
    const int TK = 32;
    __shared__ float xs[TK][68];
    __shared__ float ws[TK][68];
    int row0 = blockIdx.x * 64;
    int t = threadIdx.x;
    int tr = t >> 4, tc = t & 15;
    float acc[4][4] = {};
    for (int kb = 0; kb < 512; kb += TK) {
#pragma unroll
        for (int i = 0; i < 2; ++i) {
            int idx = t + 256 * i;
            int r = idx >> 3;
            int k4 = idx & 7;
            float4 v = make_float4(0.f, 0.f, 0.f, 0.f);
            int gr = row0 + r;
            if (gr < Nn) v = *(const float4*)(x + (size_t)gr * 512 + kb + k4 * 4);
            xs[k4 * 4 + 0][r] = v.x;
            xs[k4 * 4 + 1][r] = v.y;
            xs[k4 * 4 + 2][r] = v.z;
            xs[k4 * 4 + 3][r] = v.w;
        }
#pragma unroll
        for (int i = 0; i < 2; ++i) {
            int idx = t + 256 * i;
            int k = idx >> 4;
            int c4 = idx & 15;
            *(float4*)&ws[k][c4 * 4] =
                *(const float4*)(W1 + (size_t)(kb + k) * 64 + c4 * 4);
        }
        __syncthreads();
#pragma unroll
        for (int kk = 0; kk < TK; ++kk) {
            float4 a = *(const float4*)&xs[kk][tr * 4];
            float4 b = *(const float4*)&ws[kk][tc * 4];
            acc[0][0] += a.x * b.x; acc[0][1] += a.x * b.y; acc[0][2] += a.x * b.z; acc[0][3] += a.x * b.w;
            acc[1][0] += a.y * b.x; acc[1][1] += a.y * b.y; acc[1][2] += a.y * b.z; acc[1][3] += a.y * b.w;
            acc[2][0] += a.z * b.x; acc[2][1] += a.z * b.y; acc[2][2] += a.z * b.z; acc[2][3] += a.z * b.w;
            acc[3][0] += a.w * b.x; acc[3][1] += a.w * b.y; acc[3][2] += a.w * b.z; acc[3][3] += a.w * b.w;
        }
        __syncthreads();
    }
#pragma unroll
    for (int i = 0; i < 4; ++i) {
        int gr = row0 + tr * 4 + i;
        if (gr < Nn) {
            float4 v = make_float4(acc[i][0], acc[i][1], acc[i][2], acc[i][3]);
            *(float4*)(h1 + (size_t)gr * 64 + tc * 4) = v;
        }
    }
}

// ---------------------------------------------------------------------------
// K2: per-(node,head) attention dots for layer 1
// ---------------------------------------------------------------------------
__global__ void attn1_k(const float* __restrict__ h1, const float* __restrict__ asrc,
                        const float* __restrict__ adst, float* __restrict__ as1,
                        float* __restrict__ ad1, int Nn)
{
    int tid = blockIdx.x * 256 + threadIdx.x;
    if (tid >= Nn * 8) return;
    int n = tid >> 3, h = tid & 7;
    const float* hp = h1 + (size_t)n * 64 + h * 8;
    float s = 0.f, d = 0.f;
#pragma unroll
    for (int c = 0; c < 8; ++c) {
        float v = hp[c];
        s += v * asrc[h * 8 + c];
        d += v * adst[h * 8 + c];
    }
    as1[tid] = s;
    ad1[tid] = d;
}

// ---------------------------------------------------------------------------
// CSR build: fused histogram+rank -> 3-kernel exclusive scan -> atomic-free
// scatter. rank[e] (the atomicAdd return) gives each edge its slot within
// its dst segment, so the scatter needs no second atomic pass.
// ---------------------------------------------------------------------------
__global__ void hist_rank_k(const int* __restrict__ ei, int E, int Nn,
                            int* __restrict__ deg, int* __restrict__ rank)
{
    int e = blockIdx.x * 256 + threadIdx.x;
    int Ep = E + Nn;
    if (e >= Ep) return;
    int d = (e < E) ? ei[E + e] : e - E;
    rank[e] = atomicAdd(&deg[d], 1);
}

__global__ void scan_a_k(const int* __restrict__ deg, int Nn, int* __restrict__ bsum)
{
    __shared__ int tmp[256];
    int t = threadIdx.x;
    int base = blockIdx.x * 1024 + t * 4;
    int s = 0;
#pragma unroll
    for (int j = 0; j < 4; ++j) { int i = base + j; if (i < Nn) s += deg[i]; }
    tmp[t] = s;
    __syncthreads();
    for (int off = 1; off < 256; off <<= 1) {
        int a = (t >= off) ? tmp[t - off] : 0;
        __syncthreads();
        tmp[t] += a;
        __syncthreads();
    }
    if (t == 255) bsum[blockIdx.x] = tmp[255];
}

__global__ void scan_b_k(int* __restrict__ bsum, int nb)
{
    __shared__ int tmp[256];
    int t = threadIdx.x;
    int v = (t < nb) ? bsum[t] : 0;
    tmp[t] = v;
    __syncthreads();
    for (int off = 1; off < 256; off <<= 1) {
        int a = (t >= off) ? tmp[t - off] : 0;
        __syncthreads();
        tmp[t] += a;
        __syncthreads();
    }
    if (t < nb) bsum[t] = tmp[t] - v;  // exclusive
}

// rowptr has Nn+1 entries
__global__ void scan_c_k(const int* __restrict__ deg, int Nn, const int* __restrict__ boff,
                         int* __restrict__ rowptr)
{
    __shared__ int tmp[256];
    int t = threadIdx.x;
    int base = blockIdx.x * 1024 + t * 4;
    int v[4];
    int s = 0;
#pragma unroll
    for (int j = 0; j < 4; ++j) {
        int i = base + j;
        v[j] = (i < Nn) ? deg[i] : 0;
        s += v[j];
    }
    tmp[t] = s;
    __syncthreads();
    for (int off = 1; off < 256; off <<= 1) {
        int a = (t >= off) ? tmp[t - off] : 0;
        __syncthreads();
        tmp[t] += a;
        __syncthreads();
    }
    int excl = boff[blockIdx.x] + tmp[t] - s;
#pragma unroll
    for (int j = 0; j < 4; ++j) {
        int i = base + j;
        if (i < Nn) {
            rowptr[i] = excl;
            excl += v[j];
            if (i == Nn - 1) rowptr[Nn] = excl;
        }
    }
}

__global__ void scat2_k(const int* __restrict__ ei, int E, int Nn,
                        const int* __restrict__ rowptr, const int* __restrict__ rank,
                        int* __restrict__ csr)
{
    int e = blockIdx.x * 256 + threadIdx.x;
    int Ep = E + Nn;
    if (e >= Ep) return;
    int s, d;
    if (e < E) { s = ei[e]; d = ei[E + e]; } else { s = d = e - E; }
    csr[rowptr[d] + rank[e]] = s;
}

// ---------------------------------------------------------------------------
// Layer-1 fused softmax+aggregate: one wave per dst node.
// lane = sub*16 + c4 (sub = edge slot, c4 = float4 chunk of the 64-ch row).
// 4-deep unroll -> 16 edge gathers in flight per wave.
// ---------------------------------------------------------------------------
__global__ __launch_bounds__(256) void agg1_k(const int* __restrict__ csr,
                                              const int* __restrict__ rowptr,
                                              const float* __restrict__ as1,
                                              const float* __restrict__ ad1,
                                              const float* __restrict__ h1,
                                              float* __restrict__ out1, int Nn)
{
    int wid = (blockIdx.x * 256 + threadIdx.x) >> 6;
    if (wid >= Nn) return;
    int lane = threadIdx.x & 63;
    int sub = lane >> 4;
    int c4 = lane & 15;
    int h = c4 >> 1;
    float adv = ad1[wid * 8 + h];
    int start = rowptr[wid];
    int len = rowptr[wid + 1] - start;
    float accp = 0.f;
    float4 accv = make_float4(0.f, 0.f, 0.f, 0.f);
    int i = sub;
    for (; i + 12 < len; i += 16) {
        int s0 = csr[start + i];
        int s1 = csr[start + i + 4];
        int s2 = csr[start + i + 8];
        int s3 = csr[start + i + 12];
        float e0 = as1[s0 * 8 + h] + adv;
        float e1 = as1[s1 * 8 + h] + adv;
        float e2 = as1[s2 * 8 + h] + adv;
        float e3 = as1[s3 * 8 + h] + adv;
        float4 hv0 = *(const float4*)(h1 + (size_t)s0 * 64 + c4 * 4);
        float4 hv1 = *(const float4*)(h1 + (size_t)s1 * 64 + c4 * 4);
        float4 hv2 = *(const float4*)(h1 + (size_t)s2 * 64 + c4 * 4);
        float4 hv3 = *(const float4*)(h1 + (size_t)s3 * 64 + c4 * 4);
        e0 = e0 > 0.f ? e0 : NEG * e0;
        e1 = e1 > 0.f ? e1 : NEG * e1;
        e2 = e2 > 0.f ? e2 : NEG * e2;
        e3 = e3 > 0.f ? e3 : NEG * e3;
        float p0 = __expf(e0), p1 = __expf(e1), p2 = __expf(e2), p3 = __expf(e3);
        accp += (p0 + p1) + (p2 + p3);
        accv.x += p0 * hv0.x + p1 * hv1.x + p2 * hv2.x + p3 * hv3.x;
        accv.y += p0 * hv0.y + p1 * hv1.y + p2 * hv2.y + p3 * hv3.y;
        accv.z += p0 * hv0.z + p1 * hv1.z + p2 * hv2.z + p3 * hv3.z;
        accv.w += p0 * hv0.w + p1 * hv1.w + p2 * hv2.w + p3 * hv3.w;
    }
    for (; i < len; i += 4) {
        int s0 = csr[start + i];
        float e0 = as1[s0 * 8 + h] + adv;
        float4 hv0 = *(const float4*)(h1 + (size_t)s0 * 64 + c4 * 4);
        e0 = e0 > 0.f ? e0 : NEG * e0;
        float p0 = __expf(e0);
        accp += p0;
        accv.x += p0 * hv0.x;
        accv.y += p0 * hv0.y;
        accv.z += p0 * hv0.z;
        accv.w += p0 * hv0.w;
    }
    accp   += __shfl_xor(accp, 16);
    accv.x += __shfl_xor(accv.x, 16);
    accv.y += __shfl_xor(accv.y, 16);
    accv.z += __shfl_xor(accv.z, 16);
    accv.w += __shfl_xor(accv.w, 16);
    accp   += __shfl_xor(accp, 32);
    accv.x += __shfl_xor(accv.x, 32);
    accv.y += __shfl_xor(accv.y, 32);
    accv.z += __shfl_xor(accv.z, 32);
    accv.w += __shfl_xor(accv.w, 32);
    if (sub == 0) {
        float inv = 1.f / (accp + 1e-16f);
        float4 o = make_float4(accv.x * inv, accv.y * inv, accv.z * inv, accv.w * inv);
        *(float4*)(out1 + (size_t)wid * 64 + c4 * 4) = o;
    }
}

// ---------------------------------------------------------------------------
// K5: fused bias + ELU + GEMM2(64x10) + layer-2 attention dots (thread/node)
// h2 rows padded to stride 16 (one aligned 64B line per row)
// ---------------------------------------------------------------------------
__global__ void node2_k(const float* __restrict__ out1, const float* __restrict__ b1,
                        const float* __restrict__ W2, const float* __restrict__ as2w,
                        const float* __restrict__ ad2w, float* __restrict__ h2,
                        float* __restrict__ as2, float* __restrict__ ad2, int Nn)
{
    int n = blockIdx.x * 256 + threadIdx.x;
    if (n >= Nn) return;
    float g[64];
#pragma unroll
    for (int c = 0; c < 16; ++c) {
        float4 v = *(const float4*)(out1 + (size_t)n * 64 + c * 4);
        float4 b = *(const float4*)(b1 + c * 4);
        float t0 = v.x + b.x, t1 = v.y + b.y, t2 = v.z + b.z, t3 = v.w + b.w;
        g[c * 4 + 0] = t0 > 0.f ? t0 : expm1f(t0);
        g[c * 4 + 1] = t1 > 0.f ? t1 : expm1f(t1);
        g[c * 4 + 2] = t2 > 0.f ? t2 : expm1f(t2);
        g[c * 4 + 3] = t3 > 0.f ? t3 : expm1f(t3);
    }
    float acc[10] = {};
#pragma unroll
    for (int k = 0; k < 64; ++k) {
#pragma unroll
        for (int j = 0; j < 10; ++j) acc[j] += g[k] * W2[k * 10 + j];
    }
    float s = 0.f, d = 0.f;
#pragma unroll
    for (int j = 0; j < 10; ++j) {
        h2[(size_t)n * 16 + j] = acc[j];
        s += acc[j] * as2w[j];
        d += acc[j] * ad2w[j];
    }
    as2[n] = s;
    ad2[n] = d;
}

// ---------------------------------------------------------------------------
// Layer-2 fused softmax+aggregate: one wave per dst, lane = sub*16 + c,
// 4-deep unroll -> 16 edges in flight.
// ---------------------------------------------------------------------------
__global__ __launch_bounds__(256) void agg2_k(const int* __restrict__ csr,
                                              const int* __restrict__ rowptr,
                                              const float* __restrict__ as2,
                                              const float* __restrict__ ad2,
                                              const float* __restrict__ h2,
                                              float* __restrict__ out, int Nn)
{
    int wid = (blockIdx.x * 256 + threadIdx.x) >> 6;
    if (wid >= Nn) return;
    int lane = threadIdx.x & 63;
    int sub = lane >> 4;
    int c = lane & 15;
    float adv = ad2[wid];
    int start = rowptr[wid];
    int len = rowptr[wid + 1] - start;
    float accp = 0.f, accv = 0.f;
    int i = sub;
    for (; i + 12 < len; i += 16) {
        int s0 = csr[start + i];
        int s1 = csr[start + i + 4];
        int s2 = csr[start + i + 8];
        int s3 = csr[start + i + 12];
        float e0 = as2[s0] + adv;
        float e1 = as2[s1] + adv;
        float e2 = as2[s2] + adv;
        float e3 = as2[s3] + adv;
        float v0 = (c < 10) ? h2[(size_t)s0 * 16 + c] : 0.f;
        float v1 = (c < 10) ? h2[(size_t)s1 * 16 + c] : 0.f;
        float v2 = (c < 10) ? h2[(size_t)s2 * 16 + c] : 0.f;
        float v3 = (c < 10) ? h2[(size_t)s3 * 16 + c] : 0.f;
        e0 = e0 > 0.f ? e0 : NEG * e0;
        e1 = e1 > 0.f ? e1 : NEG * e1;
        e2 = e2 > 0.f ? e2 : NEG * e2;
        e3 = e3 > 0.f ? e3 : NEG * e3;
        float p0 = __expf(e0), p1 = __expf(e1), p2 = __expf(e2), p3 = __expf(e3);
        accp += (p0 + p1) + (p2 + p3);
        accv += p0 * v0 + p1 * v1 + p2 * v2 + p3 * v3;
    }
    for (; i < len; i += 4) {
        int s0 = csr[start + i];
        float e0 = as2[s0] + adv;
        float v0 = (c < 10) ? h2[(size_t)s0 * 16 + c] : 0.f;
        e0 = e0 > 0.f ? e0 : NEG * e0;
        float p0 = __expf(e0);
        accp += p0;
        accv += p0 * v0;
    }
    accp += __shfl_xor(accp, 16);
    accv += __shfl_xor(accv, 16);
    accp += __shfl_xor(accp, 32);
    accv += __shfl_xor(accv, 32);
    if (sub == 0 && c < 10)
        out[(size_t)wid * 10 + c] = accv / (accp + 1e-16f);
}

// ---------------------------------------------------------------------------
// K8: in-place bias + log_softmax on d_out (thread/node)
// ---------------------------------------------------------------------------
__global__ void lsm_k(float* __restrict__ out, const float* __restrict__ b2, int Nn)
{
    int n = blockIdx.x * 256 + threadIdx.x;
    if (n >= Nn) return;
    float z[10];
    float m = -1e30f;
#pragma unroll
    for (int j = 0; j < 10; ++j) {
        z[j] = out[(size_t)n * 10 + j] + b2[j];
        m = fmaxf(m, z[j]);
    }
    float ssum = 0.f;
#pragma unroll
    for (int j = 0; j < 10; ++j) ssum += expf(z[j] - m);
    float lse = m + logf(ssum);
#pragma unroll
    for (int j = 0; j < 10; ++j) out[(size_t)n * 10 + j] = z[j] - lse;
}

// ---------------------------------------------------------------------------
extern "C" void kernel_launch(void* const* d_in, const int* in_sizes, int n_in,
                              void* d_out, int out_size, void* d_ws, size_t ws_size,
                              hipStream_t stream)
{
    const float* x     = (const float*)d_in[0];
    const float* W1    = (const float*)d_in[1];
    const float* asrc1 = (const float*)d_in[2];
    const float* adst1 = (const float*)d_in[3];
    const float* b1    = (const float*)d_in[4];
    const float* W2    = (const float*)d_in[5];
    const float* asrc2 = (const float*)d_in[6];
    const float* adst2 = (const float*)d_in[7];
    const float* b2    = (const float*)d_in[8];
    const int*   ei    = (const int*)d_in[9];
    float* out = (float*)d_out;

    int F  = in_sizes[1] / 64;       // 512
    int Nn = in_sizes[0] / F;        // 100000
    int E  = in_sizes[9] / 2;        // 1600000
    int Ep = E + Nn;
    int nb = (Nn + 1023) / 1024;

    float* f = (float*)d_ws;
    float* h1   = f;  f += (size_t)Nn * 64;
    float* as1  = f;  f += (size_t)Nn * 8;
    float* ad1  = f;  f += (size_t)Nn * 8;
    float* h2   = f;  f += (size_t)Nn * 16;
    float* as2  = f;  f += Nn;
    float* ad2  = f;  f += Nn;
    float* out1 = f;  f += (size_t)Nn * 64;
    int* ip = (int*)f;
    int* deg    = ip;  ip += Nn;
    int* rowptr = ip;  ip += Nn + 1;
    int* bsum   = ip;  ip += 256;
    int* rank   = ip;  ip += Ep;
    int* csr    = ip;  ip += Ep;

    // CSR build (shared by both layers)
    hipMemsetAsync(deg, 0, (size_t)Nn * sizeof(int), stream);
    hist_rank_k<<<(Ep + 255) / 256, 256, 0, stream>>>(ei, E, Nn, deg, rank);
    scan_a_k<<<nb, 256, 0, stream>>>(deg, Nn, bsum);
    scan_b_k<<<1, 256, 0, stream>>>(bsum, nb);
    scan_c_k<<<nb, 256, 0, stream>>>(deg, Nn, bsum, rowptr);
    scat2_k<<<(Ep + 255) / 256, 256, 0, stream>>>(ei, E, Nn, rowptr, rank, csr);

    // Layer 1
    gemm1_k<<<(Nn + 63) / 64, 256, 0, stream>>>(x, W1, h1, Nn);
    attn1_k<<<(Nn * 8 + 255) / 256, 256, 0, stream>>>(h1, asrc1, adst1, as1, ad1, Nn);
    agg1_k<<<(Nn * 64 + 255) / 256, 256, 0, stream>>>(csr, rowptr, as1, ad1, h1, out1, Nn);

    // Layer 2
    node2_k<<<(Nn + 255) / 256, 256, 0, stream>>>(out1, b1, W2, asrc2, adst2, h2, as2, ad2, Nn);
    agg2_k<<<(Nn * 64 + 255) / 256, 256, 0, stream>>>(csr, rowptr, as2, ad2, h2, out, Nn);
    lsm_k<<<(Nn + 255) / 256, 256, 0, stream>>>(out, b2, Nn);
}